// Round 1
// baseline (3290.425 us; speedup 1.0000x reference)
//
#include <hip/hip_runtime.h>
#include <cstdint>
#include <cstring>

#define NQ 16
#define NLAYERS 8
#define BATCHN 512
#define LB 13                  // local (in-LDS) qubit bits per chunk
#define NLOC (1<<LB)           // 8192 amps per chunk
#define NCHUNK (1<<(NQ-LB))    // 8 chunks
#define NTHREADS 256
#define QPT (NLOC/4/NTHREADS)  // 8 quads (of 4 amps) per thread

typedef unsigned long long ull;

struct PassDesc {
  int layer, init, fin;
  unsigned gmask;       // 3 global qubit bits (chunk index bits)
  int nsweep;
  ull sweep[4];         // packed: t2,t3,t4 (4b @0,4,8), gateMask5 (@12), qid[5] (4b @20+4b)
  int nc;  ull ccP, ctP;   // write-folded CNOTs, qubit coords, original order
  int nfc; ull fcP, ftP;   // readout CNOTs (full coords)
};

__device__ __forceinline__ unsigned expand16(unsigned m, unsigned gmask, unsigned chunk){
  unsigned n = m, gm = gmask, cb = chunk;
  while (gm){
    int g = __ffs(gm) - 1; gm &= gm - 1;
    unsigned low = (1u<<g) - 1u;
    n = ((n & ~low) << 1) | (n & low) | ((cb & 1u) << g);
    cb >>= 1;
  }
  return n;
}
__device__ __forceinline__ int d_lpos(int q, unsigned gmask){
  return q - __popc(gmask & ((1u<<q) - 1u));
}
__device__ __forceinline__ unsigned swz(unsigned q){ return q ^ ((q >> 3) & 7u); }

template<int J>
__device__ __forceinline__ void apply_gate(float2 (&a)[32],
  float M0r,float M0i,float M1r,float M1i,float M2r,float M2i,float M3r,float M3i){
  #pragma unroll
  for (int b=0;b<32;b++){
    if ((b>>J)&1) continue;
    const int i0=b, i1=b|(1<<J);
    float ar=a[i0].x, ai=a[i0].y, br=a[i1].x, bi=a[i1].y;
    a[i0].x = M0r*ar - M0i*ai + M1r*br - M1i*bi;
    a[i0].y = M0r*ai + M0i*ar + M1r*bi + M1i*br;
    a[i1].x = M2r*ar - M2i*ai + M3r*br - M3i*bi;
    a[i1].y = M2r*ai + M2i*ar + M3r*bi + M3i*br;
  }
}

__global__ __launch_bounds__(NTHREADS)
void qpass(const float* __restrict__ x, const float* __restrict__ w,
           float2* __restrict__ state, float* __restrict__ out, PassDesc pd)
{
  __shared__ __align__(16) float2 st[NLOC];   // exactly 64 KB
  const int tid = threadIdx.x;
  const unsigned chunk = blockIdx.x;
  const int b = blockIdx.y;
  float2* __restrict__ gst = state + ((size_t)b << NQ);

  // per-lane Rot matrix for qubit (tid&15); broadcast later via __shfl
  float mm0,mm1,mm2,mm3,mm4,mm5,mm6,mm7;
  {
    int q = tid & 15;
    float phi = w[(pd.layer*NQ+q)*3+0];
    float th  = w[(pd.layer*NQ+q)*3+1];
    float om  = w[(pd.layer*NQ+q)*3+2];
    float sh, ch; sincosf(0.5f*th, &sh, &ch);
    float spo, cpo; sincosf(-0.5f*(phi+om), &spo, &cpo);
    float smo, cmo; sincosf(-0.5f*(phi-om), &smo, &cmo);
    mm0 =  cpo*ch; mm1 =  spo*ch;     // m00 = ep*c
    mm2 = -cmo*sh; mm3 =  smo*sh;     // m01 = -conj(em)*s
    mm4 =  cmo*sh; mm5 =  smo*sh;     // m10 = em*s
    mm6 =  cpo*ch; mm7 = -spo*ch;     // m11 = conj(ep)*c
  }

  // ---- stage in ----
  if (pd.init){
    float ca[NQ], sa[NQ];
    #pragma unroll
    for (int q=0;q<NQ;q++){
      float a_ = 1.57079632679489662f * x[b*NQ+q];
      sincosf(a_, &sa[q], &ca[q]);
    }
    #pragma unroll
    for (int j=0;j<QPT;j++){
      unsigned qi = tid + j*NTHREADS;
      unsigned n0 = expand16(qi<<2, pd.gmask, chunk);
      float vh = 1.0f;
      #pragma unroll
      for (int q=2;q<NQ;q++) vh *= ((n0>>q)&1u) ? sa[q] : ca[q];
      unsigned p2 = swz(qi)*2u;
      ((float4*)st)[p2  ] = make_float4(vh*ca[0]*ca[1], 0.f, vh*sa[0]*ca[1], 0.f);
      ((float4*)st)[p2+1] = make_float4(vh*ca[0]*sa[1], 0.f, vh*sa[0]*sa[1], 0.f);
    }
  } else {
    #pragma unroll
    for (int j=0;j<QPT;j++){
      unsigned qi = tid + j*NTHREADS;
      unsigned n0 = expand16(qi<<2, pd.gmask, chunk);
      const float4* gp = (const float4*)(gst + n0);
      float4 v0 = gp[0], v1 = gp[1];
      unsigned p2 = swz(qi)*2u;
      ((float4*)st)[p2] = v0; ((float4*)st)[p2+1] = v1;
    }
  }
  __syncthreads();

  // ---- register-tiled Rot sweeps ----
  for (int sI=0; sI<pd.nsweep; sI++){
    ull sd = pd.sweep[sI];
    int t2 = (int)(sd & 15ull), t3 = (int)((sd>>4)&15ull), t4 = (int)((sd>>8)&15ull);
    unsigned gm = (unsigned)((sd>>12)&31ull);
    unsigned tmask = 3u | (1u<<t2) | (1u<<t3) | (1u<<t4);
    unsigned base = 0, src = (unsigned)tid;
    for (int bb=2; bb<LB; bb++){
      if (!((tmask>>bb)&1u)){ base |= (src&1u)<<bb; src >>= 1; }
    }
    float2 a[32];
    unsigned qaddr[8];
    #pragma unroll
    for (int g=0; g<8; g++){
      unsigned m = base | ((unsigned)(g&1)<<t2) | ((unsigned)((g>>1)&1)<<t3) | ((unsigned)((g>>2)&1)<<t4);
      unsigned p2 = swz(m>>2)*2u;
      qaddr[g] = p2;
      float4 v0 = ((float4*)st)[p2], v1 = ((float4*)st)[p2+1];
      a[g*4+0] = make_float2(v0.x,v0.y);
      a[g*4+1] = make_float2(v0.z,v0.w);
      a[g*4+2] = make_float2(v1.x,v1.y);
      a[g*4+3] = make_float2(v1.z,v1.w);
    }
    #pragma unroll
    for (int gb=0; gb<5; gb++){
      if (!((gm>>gb)&1u)) continue;
      int q = (int)((sd >> (20+4*gb)) & 15ull);
      float M0r=__shfl(mm0,q), M0i=__shfl(mm1,q), M1r=__shfl(mm2,q), M1i=__shfl(mm3,q);
      float M2r=__shfl(mm4,q), M2i=__shfl(mm5,q), M3r=__shfl(mm6,q), M3i=__shfl(mm7,q);
      switch(gb){
        case 0: apply_gate<0>(a,M0r,M0i,M1r,M1i,M2r,M2i,M3r,M3i); break;
        case 1: apply_gate<1>(a,M0r,M0i,M1r,M1i,M2r,M2i,M3r,M3i); break;
        case 2: apply_gate<2>(a,M0r,M0i,M1r,M1i,M2r,M2i,M3r,M3i); break;
        case 3: apply_gate<3>(a,M0r,M0i,M1r,M1i,M2r,M2i,M3r,M3i); break;
        case 4: apply_gate<4>(a,M0r,M0i,M1r,M1i,M2r,M2i,M3r,M3i); break;
      }
    }
    #pragma unroll
    for (int g=0; g<8; g++){
      unsigned p2 = qaddr[g];
      ((float4*)st)[p2  ] = make_float4(a[g*4+0].x,a[g*4+0].y,a[g*4+1].x,a[g*4+1].y);
      ((float4*)st)[p2+1] = make_float4(a[g*4+2].x,a[g*4+2].y,a[g*4+3].x,a[g*4+3].y);
    }
    __syncthreads();
  }

  if (!pd.fin){
    // ---- stage out, CNOT permutation folded into gather addresses ----
    ull ccL=0, ctL=0;
    for (int i=0;i<pd.nc;i++){
      int c = d_lpos((int)((pd.ccP>>(4*i))&15ull), pd.gmask);
      int t = d_lpos((int)((pd.ctP>>(4*i))&15ull), pd.gmask);
      ccL |= (ull)c << (4*i);
      ctL |= (ull)t << (4*i);
    }
    #pragma unroll
    for (int j=0;j<QPT;j++){
      unsigned qo = tid + j*NTHREADS;
      unsigned n0 = expand16(qo<<2, pd.gmask, chunk);
      float2 vv[4];
      #pragma unroll
      for (int e=0;e<4;e++){
        unsigned s2 = (qo<<2) | (unsigned)e;
        for (int i=pd.nc-1;i>=0;i--){            // source = K_k(...K_1-last...) reverse order
          int c = (int)((ccL>>(4*i))&15ull);
          int t = (int)((ctL>>(4*i))&15ull);
          s2 ^= ((s2>>c)&1u) << t;
        }
        vv[e] = st[ swz(s2>>2)*4u + (s2&3u) ];
      }
      float4* gp = (float4*)(gst + n0);
      gp[0] = make_float4(vv[0].x,vv[0].y,vv[1].x,vv[1].y);
      gp[1] = make_float4(vv[2].x,vv[2].y,vv[3].x,vv[3].y);
    }
  } else {
    // ---- readout: <Z_q> with final CNOTs folded into parity of transformed index ----
    float acc[NQ];
    #pragma unroll
    for (int q=0;q<NQ;q++) acc[q]=0.f;
    #pragma unroll
    for (int j=0;j<QPT;j++){
      unsigned qi = tid + j*NTHREADS;
      unsigned p2 = swz(qi)*2u;
      float4 v0 = ((float4*)st)[p2], v1 = ((float4*)st)[p2+1];
      unsigned n0 = expand16(qi<<2, pd.gmask, chunk);
      float pr[4] = { v0.x*v0.x+v0.y*v0.y, v0.z*v0.z+v0.w*v0.w,
                      v1.x*v1.x+v1.y*v1.y, v1.z*v1.z+v1.w*v1.w };
      #pragma unroll
      for (int e=0;e<4;e++){
        unsigned n = n0 | (unsigned)e;
        for (int i=0;i<pd.nfc;i++){              // forward order for index transform
          int c=(int)((pd.fcP>>(4*i))&15ull), t=(int)((pd.ftP>>(4*i))&15ull);
          n ^= ((n>>c)&1u)<<t;
        }
        float p = pr[e];
        #pragma unroll
        for (int q=0;q<NQ;q++) acc[q] += ((n>>q)&1u) ? -p : p;
      }
    }
    #pragma unroll
    for (int q=0;q<NQ;q++){
      float v = acc[q];
      #pragma unroll
      for (int off=32; off; off>>=1) v += __shfl_xor(v, off);
      if ((tid & 63) == 0) atomicAdd(&out[b*NQ+q], v);
    }
  }
}

static inline ull pk(int t2,int t3,int t4,unsigned gm,int q0,int q1,int q2,int q3,int q4){
  return (ull)(t2&15) | ((ull)(t3&15)<<4) | ((ull)(t4&15)<<8) | ((ull)(gm&31)<<12)
    | ((ull)(q0&15)<<20) | ((ull)(q1&15)<<24) | ((ull)(q2&15)<<28)
    | ((ull)(q3&15)<<32) | ((ull)(q4&15)<<36);
}
static inline int h_lpos(int q, unsigned gmask){
  int c=0; for(int i=0;i<q;i++) if((gmask>>i)&1u) c++;
  return q-c;
}

extern "C" void kernel_launch(void* const* d_in, const int* in_sizes, int n_in,
                              void* d_out, int out_size, void* d_ws, size_t ws_size,
                              hipStream_t stream)
{
  (void)in_sizes; (void)n_in; (void)ws_size;
  const float* x = (const float*)d_in[0];
  const float* w = (const float*)d_in[1];
  float* out = (float*)d_out;
  float2* state = (float2*)d_ws;   // needs 512*65536*8 = 256 MiB

  hipMemsetAsync(d_out, 0, (size_t)out_size*sizeof(float), stream);

  const unsigned topmask = (1u<<13)|(1u<<14)|(1u<<15);
  for (int l=0;l<NLAYERS;l++){
    int r = l % (NQ-1) + 1;

    // ---- pass A: globals {13,14,15}; Rot0..12; CNOTs untouched by top3 folded into write
    PassDesc A; memset(&A,0,sizeof(A));
    A.layer=l; A.init=(l==0); A.fin=0; A.gmask=topmask; A.nsweep=4;
    A.sweep[0]=pk(2,3,4,  0x1F, 0,1,2,3,4);
    A.sweep[1]=pk(5,6,7,  0x1C, 0,0,5,6,7);
    A.sweep[2]=pk(8,9,10, 0x1C, 0,0,8,9,10);
    A.sweep[3]=pk(11,12,2,0x0C, 0,0,11,12,0);
    int nc=0, nd=0; ull cc=0,ct=0; int dc[8], dt[8];
    unsigned T = topmask;
    for (int i=0;i<NQ;i++){
      int t=(i+r)&15;
      if (((topmask>>i)&1u) || ((topmask>>t)&1u)){
        dc[nd]=i; dt[nd]=t; nd++; T |= (1u<<i)|(1u<<t);
      } else {
        cc |= (ull)i<<(4*nc); ct |= (ull)t<<(4*nc); nc++;
      }
    }
    A.nc=nc; A.ccP=cc; A.ctP=ct;
    hipLaunchKernelGGL(qpass, dim3(NCHUNK,BATCHN), dim3(NTHREADS), 0, stream,
                       x, w, state, out, A);

    // ---- pass B: globals = 3 highest qubits not touched by deferred gates
    PassDesc B; memset(&B,0,sizeof(B));
    B.layer=l; B.init=0; B.fin=(l==NLAYERS-1);
    unsigned gB=0; int cnt=0;
    for (int q=NQ-1;q>=0 && cnt<3;q--) if(!((T>>q)&1u)){ gB|=(1u<<q); cnt++; }
    B.gmask=gB;
    int p13=h_lpos(13,gB), p14=h_lpos(14,gB), p15=h_lpos(15,gB);
    B.nsweep=1;
    B.sweep[0]=pk(p13,p14,p15, 0x1C, 0,0,13,14,15);
    if (!B.fin){
      ull bc=0,bt=0;
      for (int i=0;i<nd;i++){ bc|=(ull)dc[i]<<(4*i); bt|=(ull)dt[i]<<(4*i); }
      B.nc=nd; B.ccP=bc; B.ctP=bt;
    } else {
      ull fc=0,ft=0;
      for (int i=0;i<nd;i++){ fc|=(ull)dc[i]<<(4*i); ft|=(ull)dt[i]<<(4*i); }
      B.nfc=nd; B.fcP=fc; B.ftP=ft;
    }
    hipLaunchKernelGGL(qpass, dim3(NCHUNK,BATCHN), dim3(NTHREADS), 0, stream,
                       x, w, state, out, B);
  }
}